// Round 3
// baseline (860.899 us; speedup 1.0000x reference)
//
#include <hip/hip_runtime.h>
#include <math.h>

typedef unsigned short u16;
typedef __bf16 bf16x8_t __attribute__((ext_vector_type(8)));
typedef float f32x4_t __attribute__((ext_vector_type(4)));

#define B_  2
#define S_  2048
#define D_  2048
#define H_  16
#define G_  4
#define DH_ 128

#define NEG_SENTINEL (-3.0e38f)

__device__ __forceinline__ float b2f(u16 u) {
    union { unsigned int i; float f; } v; v.i = ((unsigned int)u) << 16; return v.f;
}
__device__ __forceinline__ u16 f2b(float f) {
    union { float f; unsigned int i; } v; v.f = f;
    unsigned int r = v.i + 0x7fffu + ((v.i >> 16) & 1u);  // RNE
    return (u16)(r >> 16);
}
__device__ __forceinline__ void stc(u16* p, float v)   { *p = f2b(v); }
__device__ __forceinline__ void stc(float* p, float v) { *p = v; }

// ---------------------------------------------------------------------------
// Cast f32 -> bf16, 8 elems/thread.  n must be divisible by 2048.
// ---------------------------------------------------------------------------
__global__ __launch_bounds__(256) void cast_x(
    const float* __restrict__ in, u16* __restrict__ out) {
    int i = (blockIdx.x * 256 + threadIdx.x) * 8;
    float4 a = *(const float4*)(in + i);
    float4 b = *(const float4*)(in + i + 4);
    u16 o[8] = {f2b(a.x), f2b(a.y), f2b(a.z), f2b(a.w),
                f2b(b.x), f2b(b.y), f2b(b.z), f2b(b.w)};
    *(uint4*)(out + i) = *(uint4*)o;
}

// ---------------------------------------------------------------------------
// Transpose + cast: in f32 [R][C] -> out bf16 [C][R]. grid=(C/32, R/32)
// ---------------------------------------------------------------------------
__global__ __launch_bounds__(256) void transpose_f32_bf16(
    const float* __restrict__ in, u16* __restrict__ out, int R, int C) {
    __shared__ u16 t[32][33];
    const int c0 = blockIdx.x * 32, r0 = blockIdx.y * 32;
    const int j = threadIdx.x & 31, i = threadIdx.x >> 5;  // i in 0..7
#pragma unroll
    for (int p = 0; p < 4; ++p)
        t[i + 8 * p][j] = f2b(in[(size_t)(r0 + i + 8 * p) * C + c0 + j]);
    __syncthreads();
#pragma unroll
    for (int p = 0; p < 4; ++p)
        out[(size_t)(c0 + i + 8 * p) * R + r0 + j] = t[j][i + 8 * p];
}

// ---------------------------------------------------------------------------
// NT GEMM: C[M][N] = A[M][K] * BT[N][K]^T (bf16 in, OT out, f32 acc)
// block = 256 (4 waves), tile 128x128, BK=64. grid=(N/128, M/128)
// ---------------------------------------------------------------------------
template <typename OT>
__global__ __launch_bounds__(256) void gemm_nt(
    const u16* __restrict__ A, const u16* __restrict__ BT, OT* __restrict__ C,
    int M, int N, int K) {
    __shared__ __align__(16) u16 As[128 * 72];  // 64 cols padded to 72
    __shared__ __align__(16) u16 Bs[128 * 72];
    const int tid  = threadIdx.x;
    const int lane = tid & 63;
    const int wave = tid >> 6;
    const int wm = wave >> 1, wn = wave & 1;
    const int quad = lane >> 4, l16 = lane & 15;
    const int m0 = blockIdx.y * 128, n0 = blockIdx.x * 128;

    f32x4_t acc[4][4] = {};

    for (int k0 = 0; k0 < K; k0 += 64) {
#pragma unroll
        for (int c = tid; c < 1024; c += 256) {
            int row = c >> 3, cc = (c & 7) << 3;
            *(uint4*)(&As[row * 72 + cc]) =
                *(const uint4*)(A + (size_t)(m0 + row) * K + k0 + cc);
            *(uint4*)(&Bs[row * 72 + cc]) =
                *(const uint4*)(BT + (size_t)(n0 + row) * K + k0 + cc);
        }
        __syncthreads();
#pragma unroll
        for (int ks = 0; ks < 2; ++ks) {
            const int koff = ks * 32 + quad * 8;
            bf16x8_t a[4], b[4];
#pragma unroll
            for (int mt = 0; mt < 4; ++mt)
                a[mt] = *(const bf16x8_t*)(&As[(wm * 64 + mt * 16 + l16) * 72 + koff]);
#pragma unroll
            for (int nt = 0; nt < 4; ++nt)
                b[nt] = *(const bf16x8_t*)(&Bs[(wn * 64 + nt * 16 + l16) * 72 + koff]);
#pragma unroll
            for (int mt = 0; mt < 4; ++mt)
#pragma unroll
                for (int nt = 0; nt < 4; ++nt)
                    acc[mt][nt] = __builtin_amdgcn_mfma_f32_16x16x32_bf16(
                        a[mt], b[nt], acc[mt][nt], 0, 0, 0);
        }
        __syncthreads();
    }
    // epilogue: C/D layout col=lane&15, row=quad*4+r
#pragma unroll
    for (int mt = 0; mt < 4; ++mt)
#pragma unroll
        for (int nt = 0; nt < 4; ++nt)
#pragma unroll
            for (int r = 0; r < 4; ++r) {
                int m = m0 + wm * 64 + mt * 16 + quad * 4 + r;
                int n = n0 + wn * 64 + nt * 16 + l16;
                stc(C + (size_t)m * N + n, acc[mt][nt][r]);
            }
}

// ---------------------------------------------------------------------------
// RoPE on q in-place (bf16).  q layout [B][S][H][DH].
// ---------------------------------------------------------------------------
__global__ __launch_bounds__(256) void rope_q(u16* q) {
    int idx = blockIdx.x * 256 + threadIdx.x;
    int d = idx & 63;
    int t = idx >> 6;
    int h = t & 15; t >>= 4;
    int s = t & 2047;
    int b = t >> 11;
    size_t base = ((size_t)(b * S_ + s) * H_ + h) * DH_;
    float x1 = b2f(q[base + d]), x2 = b2f(q[base + d + 64]);
    float inv = exp2f(-(float)d * (13.287712379549449f / 64.f));  // 10000^(-d/64)
    float ang = (float)s * inv, sn, cs;
    sincosf(ang, &sn, &cs);
    q[base + d]      = f2b(x1 * cs - x2 * sn);
    q[base + d + 64] = f2b(x2 * cs + x1 * sn);
}

// ---------------------------------------------------------------------------
// RoPE on k: kvraw bf16 [B*S][1024] (cols 0..511 = k) ->
//   kc f32 [B][G][S][DH] (output) and kb bf16 same layout (for MFMA)
// ---------------------------------------------------------------------------
__global__ __launch_bounds__(256) void k_prep(
    const u16* __restrict__ kvraw, float* __restrict__ kc, u16* __restrict__ kb) {
    int idx = blockIdx.x * 256 + threadIdx.x;
    int d = idx & 63;
    int t = idx >> 6;
    int g = t & 3; t >>= 2;
    int s = t & 2047;
    int b = t >> 11;
    const u16* src = kvraw + (size_t)(b * S_ + s) * 1024 + g * DH_;
    float x1 = b2f(src[d]), x2 = b2f(src[d + 64]);
    float inv = exp2f(-(float)d * (13.287712379549449f / 64.f));
    float ang = (float)s * inv, sn, cs;
    sincosf(ang, &sn, &cs);
    float r1 = x1 * cs - x2 * sn;
    float r2 = x2 * cs + x1 * sn;
    size_t o = ((size_t)(b * G_ + g) * S_ + s) * DH_;
    kc[o + d]      = r1;
    kc[o + d + 64] = r2;
    kb[o + d]      = f2b(r1);
    kb[o + d + 64] = f2b(r2);
}

// ---------------------------------------------------------------------------
// v: emit v_cache f32 [B][G][S][DH] and v^T bf16 [B][G][DH][S]
// grid=(S/32, DH/32, B*G), block=256
// ---------------------------------------------------------------------------
__global__ __launch_bounds__(256) void v_prep(
    const u16* __restrict__ kvraw, float* __restrict__ vc, u16* __restrict__ vt) {
    __shared__ u16 t[32][33];
    const int s0 = blockIdx.x * 32, d0 = blockIdx.y * 32;
    const int bg = blockIdx.z, b = bg >> 2, g = bg & 3;
    const int j = threadIdx.x & 31, i = threadIdx.x >> 5;
#pragma unroll
    for (int p = 0; p < 4; ++p) {
        int s = s0 + i + 8 * p;
        u16 v = kvraw[(size_t)(b * S_ + s) * 1024 + 512 + g * DH_ + d0 + j];
        t[i + 8 * p][j] = v;
        vc[((size_t)bg * S_ + s) * DH_ + d0 + j] = b2f(v);
    }
    __syncthreads();
#pragma unroll
    for (int p = 0; p < 4; ++p)
        vt[((size_t)bg * DH_ + d0 + i + 8 * p) * S_ + s0 + j] = t[j][i + 8 * p];
}

// ---------------------------------------------------------------------------
// Flash attention, causal. 1 wave per (b, h, 32 q-rows). grid=(S/32, H, B)
// All bf16 inputs; no infinity arithmetic (fast-math safe).
// ---------------------------------------------------------------------------
__global__ __launch_bounds__(64) void flash_attn(
    const u16* __restrict__ q, const u16* __restrict__ kb,
    const u16* __restrict__ vt, u16* __restrict__ ctx) {
    const int lane = threadIdx.x;
    const int quad = lane >> 4, l16 = lane & 15;
    const int q0 = blockIdx.x * 32;
    const int h = blockIdx.y, b = blockIdx.z;
    const int g = h >> 2;  // H/G = 4
    const u16* Kp = kb + (size_t)(b * G_ + g) * S_ * DH_;
    const u16* Vt = vt + (size_t)(b * G_ + g) * DH_ * S_;
    const float sc = 0.08838834764831843f * 1.4426950408889634f;  // 1/sqrt(128)*log2(e)

    // Q fragments: A-layout [m=lane&15][k=quad*8+j]
    bf16x8_t qf[2][4];
#pragma unroll
    for (int mt = 0; mt < 2; ++mt)
#pragma unroll
        for (int kt = 0; kt < 4; ++kt)
            qf[mt][kt] = *(const bf16x8_t*)(
                q + ((size_t)(b * S_ + q0 + mt * 16 + l16) * H_ + h) * DH_ + kt * 32 + quad * 8);

    f32x4_t o[2][8] = {};
    float m_i[2][4], l_i[2][4];
#pragma unroll
    for (int mt = 0; mt < 2; ++mt)
#pragma unroll
        for (int r = 0; r < 4; ++r) { m_i[mt][r] = NEG_SENTINEL; l_i[mt][r] = 0.f; }

    __shared__ __align__(16) u16 Plds[32 * 72];

    const int kv_end = q0 + 32;
    for (int kv0 = 0; kv0 < kv_end; kv0 += 64) {
        // S = Q K^T  (2 m-tiles x 4 n-tiles, K=128 over 4 steps)
        f32x4_t s[2][4] = {};
#pragma unroll
        for (int kt = 0; kt < 4; ++kt) {
            bf16x8_t kbf[4];
#pragma unroll
            for (int nt = 0; nt < 4; ++nt)
                kbf[nt] = *(const bf16x8_t*)(
                    Kp + (size_t)(kv0 + nt * 16 + l16) * DH_ + kt * 32 + quad * 8);
#pragma unroll
            for (int mt = 0; mt < 2; ++mt)
#pragma unroll
                for (int nt = 0; nt < 4; ++nt)
                    s[mt][nt] = __builtin_amdgcn_mfma_f32_16x16x32_bf16(
                        qf[mt][kt], kbf[nt], s[mt][nt], 0, 0, 0);
        }
        // causal mask — finite sentinel, no inf
        if (kv0 + 63 > q0) {
#pragma unroll
            for (int mt = 0; mt < 2; ++mt)
#pragma unroll
                for (int nt = 0; nt < 4; ++nt)
#pragma unroll
                    for (int r = 0; r < 4; ++r) {
                        int row = q0 + mt * 16 + quad * 4 + r;
                        int col = kv0 + nt * 16 + l16;
                        if (col > row) s[mt][nt][r] = NEG_SENTINEL;
                    }
        }
        // online softmax (rows live across the 16-lane group of this quad)
#pragma unroll
        for (int mt = 0; mt < 2; ++mt)
#pragma unroll
            for (int r = 0; r < 4; ++r) {
                float mx = fmaxf(fmaxf(s[mt][0][r], s[mt][1][r]),
                                 fmaxf(s[mt][2][r], s[mt][3][r]));
#pragma unroll
                for (int off = 8; off >= 1; off >>= 1)
                    mx = fmaxf(mx, __shfl_xor(mx, off));
                float mnew  = fmaxf(m_i[mt][r], mx);
                float alpha = exp2f(fminf((m_i[mt][r] - mnew) * sc, 0.f));
                m_i[mt][r]  = mnew;
                float rs = 0.f;
#pragma unroll
                for (int nt = 0; nt < 4; ++nt) {
                    float p = exp2f(fminf((s[mt][nt][r] - mnew) * sc, 0.f));
                    if (s[mt][nt][r] <= NEG_SENTINEL * 0.5f) p = 0.f;  // masked -> 0
                    s[mt][nt][r] = p;
                    rs += p;
                }
#pragma unroll
                for (int off = 8; off >= 1; off >>= 1)
                    rs += __shfl_xor(rs, off);
                l_i[mt][r] = l_i[mt][r] * alpha + rs;
#pragma unroll
                for (int nt = 0; nt < 8; ++nt) o[mt][nt][r] *= alpha;
            }
        // P: C/D layout -> LDS -> A-operand layout
#pragma unroll
        for (int mt = 0; mt < 2; ++mt)
#pragma unroll
            for (int nt = 0; nt < 4; ++nt)
#pragma unroll
                for (int r = 0; r < 4; ++r)
                    Plds[(mt * 16 + quad * 4 + r) * 72 + nt * 16 + l16] = f2b(s[mt][nt][r]);
        __syncthreads();
        // O += P V
#pragma unroll
        for (int ks = 0; ks < 2; ++ks) {
            bf16x8_t pa[2];
#pragma unroll
            for (int mt = 0; mt < 2; ++mt)
                pa[mt] = *(const bf16x8_t*)(&Plds[(mt * 16 + l16) * 72 + ks * 32 + quad * 8]);
#pragma unroll
            for (int nt = 0; nt < 8; ++nt) {
                bf16x8_t vb = *(const bf16x8_t*)(
                    Vt + (size_t)(nt * 16 + l16) * S_ + kv0 + ks * 32 + quad * 8);
#pragma unroll
                for (int mt = 0; mt < 2; ++mt)
                    o[mt][nt] = __builtin_amdgcn_mfma_f32_16x16x32_bf16(
                        pa[mt], vb, o[mt][nt], 0, 0, 0);
            }
        }
        __syncthreads();
    }
    // epilogue
#pragma unroll
    for (int mt = 0; mt < 2; ++mt)
#pragma unroll
        for (int r = 0; r < 4; ++r) {
            float inv = 1.f / l_i[mt][r];
            int s_idx = q0 + mt * 16 + quad * 4 + r;
#pragma unroll
            for (int nt = 0; nt < 8; ++nt)
                ctx[((size_t)(b * S_ + s_idx) * H_ + h) * DH_ + nt * 16 + l16] =
                    f2b(o[mt][nt][r] * inv);
        }
}

// ---------------------------------------------------------------------------
extern "C" void kernel_launch(void* const* d_in, const int* in_sizes, int n_in,
                              void* d_out, int out_size, void* d_ws, size_t ws_size,
                              hipStream_t stream) {
    const float* x  = (const float*)d_in[0];
    const float* Wq = (const float*)d_in[1];
    const float* Wk = (const float*)d_in[2];
    const float* Wv = (const float*)d_in[3];
    const float* Wo = (const float*)d_in[4];
    // d_in[5] = mask (unused; causal computed analytically)

    float* out    = (float*)d_out;                           // [B][S][H*DH]  8,388,608 f32
    float* kc_out = out + (size_t)B_ * S_ * H_ * DH_;        // [B][G][S][DH] 2,097,152 f32
    float* vc_out = kc_out + (size_t)B_ * G_ * S_ * DH_;     // [B][G][S][DH] 2,097,152 f32

    // Borrow `out` f32 region (= 16M u16) as early scratch; both buffers are
    // dead before the final gemm writes `out` (single stream, serialized).
    u16* outw = (u16*)d_out;
    u16* xb   = outw;             // 8M u16, live phases 1-2 (x cast to bf16)
    u16* qraw = outw + 8388608;   // 8M u16, live phases 2-4

    // Workspace: 16M u16 = 32 MiB, phase-safe overlays
    u16* ws    = (u16*)d_ws;
    u16* WqT   = ws;              // 4M, phases 1-2
    u16* WoT   = ws;              // 4M, phases 3-5 (transposed after q-gemm)
    u16* WkvT  = ws + 4194304;    // 2M, phases 1-2
    u16* kb    = ws + 4194304;    // 2M, phases 3-4
    u16* vt    = ws + 6291456;    // 2M, phases 3-4
    u16* kvraw = ws + 8388608;    // 4M, phases 2-3
    u16* ctx   = ws + 8388608;    // 8M, phases 4-5

    dim3 blk(256);
    // phase 1: casts + W transposes
    cast_x<<<dim3(4096), blk, 0, stream>>>(x, xb);
    transpose_f32_bf16<<<dim3(64, 64), blk, 0, stream>>>(Wq, WqT, 2048, 2048);
    transpose_f32_bf16<<<dim3(16, 64), blk, 0, stream>>>(Wk, WkvT, 2048, 512);
    transpose_f32_bf16<<<dim3(16, 64), blk, 0, stream>>>(Wv, WkvT + (size_t)512 * 2048, 2048, 512);

    // phase 2: projections
    gemm_nt<u16><<<dim3(16, 32), blk, 0, stream>>>(xb, WqT, qraw, 4096, 2048, 2048);
    gemm_nt<u16><<<dim3(8, 32),  blk, 0, stream>>>(xb, WkvT, kvraw, 4096, 1024, 2048);

    // phase 3: RoPE + cache outputs (+ Wo transpose into WqT's slot)
    transpose_f32_bf16<<<dim3(64, 64), blk, 0, stream>>>(Wo, WoT, 2048, 2048);
    rope_q<<<dim3(16384), blk, 0, stream>>>(qraw);
    k_prep<<<dim3(4096),  blk, 0, stream>>>(kvraw, kc_out, kb);
    v_prep<<<dim3(64, 4, 8), blk, 0, stream>>>(kvraw, vc_out, vt);

    // phase 4: attention
    flash_attn<<<dim3(64, 16, 2), dim3(64), 0, stream>>>(qraw, kb, vt, ctx);

    // phase 5: output projection (f32 out)
    gemm_nt<float><<<dim3(16, 32), blk, 0, stream>>>(ctx, WoT, out, 4096, 2048, 2048);
}

// Round 4
// 728.757 us; speedup vs baseline: 1.1813x; 1.1813x over previous
//
#include <hip/hip_runtime.h>
#include <math.h>

typedef unsigned short u16;
typedef __bf16 bf16x8_t __attribute__((ext_vector_type(8)));
typedef float f32x4_t __attribute__((ext_vector_type(4)));

#define B_  2
#define S_  2048
#define D_  2048
#define H_  16
#define G_  4
#define DH_ 128

#define NEG_SENTINEL (-3.0e38f)

__device__ __forceinline__ float b2f(u16 u) {
    union { unsigned int i; float f; } v; v.i = ((unsigned int)u) << 16; return v.f;
}
__device__ __forceinline__ u16 f2b(float f) {
    union { float f; unsigned int i; } v; v.f = f;
    unsigned int r = v.i + 0x7fffu + ((v.i >> 16) & 1u);  // RNE
    return (u16)(r >> 16);
}
__device__ __forceinline__ void stc(u16* p, float v)   { *p = f2b(v); }
__device__ __forceinline__ void stc(float* p, float v) { *p = v; }

// ---------------------------------------------------------------------------
// Cast f32 -> bf16, 8 elems/thread.
// ---------------------------------------------------------------------------
__global__ __launch_bounds__(256) void cast_x(
    const float* __restrict__ in, u16* __restrict__ out) {
    int i = (blockIdx.x * 256 + threadIdx.x) * 8;
    float4 a = *(const float4*)(in + i);
    float4 b = *(const float4*)(in + i + 4);
    u16 o[8] = {f2b(a.x), f2b(a.y), f2b(a.z), f2b(a.w),
                f2b(b.x), f2b(b.y), f2b(b.z), f2b(b.w)};
    *(uint4*)(out + i) = *(uint4*)o;
}

// ---------------------------------------------------------------------------
// Transpose + cast: in f32 [R][C] -> out bf16 [C][R]. grid=(C/32, R/32)
// ---------------------------------------------------------------------------
__global__ __launch_bounds__(256) void transpose_f32_bf16(
    const float* __restrict__ in, u16* __restrict__ out, int R, int C) {
    __shared__ u16 t[32][33];
    const int c0 = blockIdx.x * 32, r0 = blockIdx.y * 32;
    const int j = threadIdx.x & 31, i = threadIdx.x >> 5;  // i in 0..7
#pragma unroll
    for (int p = 0; p < 4; ++p)
        t[i + 8 * p][j] = f2b(in[(size_t)(r0 + i + 8 * p) * C + c0 + j]);
    __syncthreads();
#pragma unroll
    for (int p = 0; p < 4; ++p)
        out[(size_t)(c0 + i + 8 * p) * R + r0 + j] = t[j][i + 8 * p];
}

// ---------------------------------------------------------------------------
// NT GEMM: C[M][N] = A[M][K] * BT[N][K]^T (bf16 in, OT out, f32 acc)
// block = 256 (4 waves), tile 128x128, BK=64. grid=(N/128, M/128)
// ---------------------------------------------------------------------------
template <typename OT>
__global__ __launch_bounds__(256) void gemm_nt(
    const u16* __restrict__ A, const u16* __restrict__ BT, OT* __restrict__ C,
    int M, int N, int K) {
    __shared__ __align__(16) u16 As[128 * 72];
    __shared__ __align__(16) u16 Bs[128 * 72];
    const int tid  = threadIdx.x;
    const int lane = tid & 63;
    const int wave = tid >> 6;
    const int wm = wave >> 1, wn = wave & 1;
    const int quad = lane >> 4, l16 = lane & 15;
    const int m0 = blockIdx.y * 128, n0 = blockIdx.x * 128;

    f32x4_t acc[4][4] = {};

    for (int k0 = 0; k0 < K; k0 += 64) {
#pragma unroll
        for (int c = tid; c < 1024; c += 256) {
            int row = c >> 3, cc = (c & 7) << 3;
            *(uint4*)(&As[row * 72 + cc]) =
                *(const uint4*)(A + (size_t)(m0 + row) * K + k0 + cc);
            *(uint4*)(&Bs[row * 72 + cc]) =
                *(const uint4*)(BT + (size_t)(n0 + row) * K + k0 + cc);
        }
        __syncthreads();
#pragma unroll
        for (int ks = 0; ks < 2; ++ks) {
            const int koff = ks * 32 + quad * 8;
            bf16x8_t a[4], b[4];
#pragma unroll
            for (int mt = 0; mt < 4; ++mt)
                a[mt] = *(const bf16x8_t*)(&As[(wm * 64 + mt * 16 + l16) * 72 + koff]);
#pragma unroll
            for (int nt = 0; nt < 4; ++nt)
                b[nt] = *(const bf16x8_t*)(&Bs[(wn * 64 + nt * 16 + l16) * 72 + koff]);
#pragma unroll
            for (int mt = 0; mt < 4; ++mt)
#pragma unroll
                for (int nt = 0; nt < 4; ++nt)
                    acc[mt][nt] = __builtin_amdgcn_mfma_f32_16x16x32_bf16(
                        a[mt], b[nt], acc[mt][nt], 0, 0, 0);
        }
        __syncthreads();
    }
#pragma unroll
    for (int mt = 0; mt < 4; ++mt)
#pragma unroll
        for (int nt = 0; nt < 4; ++nt)
#pragma unroll
            for (int r = 0; r < 4; ++r) {
                int m = m0 + wm * 64 + mt * 16 + quad * 4 + r;
                int n = n0 + wn * 64 + nt * 16 + l16;
                stc(C + (size_t)m * N + n, acc[mt][nt][r]);
            }
}

// ---------------------------------------------------------------------------
// RoPE on q in-place (bf16).  q layout [B][S][H][DH].
// ---------------------------------------------------------------------------
__global__ __launch_bounds__(256) void rope_q(u16* q) {
    int idx = blockIdx.x * 256 + threadIdx.x;
    int d = idx & 63;
    int t = idx >> 6;
    int h = t & 15; t >>= 4;
    int s = t & 2047;
    int b = t >> 11;
    size_t base = ((size_t)(b * S_ + s) * H_ + h) * DH_;
    float x1 = b2f(q[base + d]), x2 = b2f(q[base + d + 64]);
    float inv = exp2f(-(float)d * (13.287712379549449f / 64.f));  // 10000^(-d/64)
    float ang = (float)s * inv, sn, cs;
    sincosf(ang, &sn, &cs);
    q[base + d]      = f2b(x1 * cs - x2 * sn);
    q[base + d + 64] = f2b(x2 * cs + x1 * sn);
}

// ---------------------------------------------------------------------------
// RoPE on k: kvraw bf16 [B*S][1024] (cols 0..511 = k) ->
//   kc f32 [B][G][S][DH] (output) and kb bf16 same layout (for MFMA)
// ---------------------------------------------------------------------------
__global__ __launch_bounds__(256) void k_prep(
    const u16* __restrict__ kvraw, float* __restrict__ kc, u16* __restrict__ kb) {
    int idx = blockIdx.x * 256 + threadIdx.x;
    int d = idx & 63;
    int t = idx >> 6;
    int g = t & 3; t >>= 2;
    int s = t & 2047;
    int b = t >> 11;
    const u16* src = kvraw + (size_t)(b * S_ + s) * 1024 + g * DH_;
    float x1 = b2f(src[d]), x2 = b2f(src[d + 64]);
    float inv = exp2f(-(float)d * (13.287712379549449f / 64.f));
    float ang = (float)s * inv, sn, cs;
    sincosf(ang, &sn, &cs);
    float r1 = x1 * cs - x2 * sn;
    float r2 = x2 * cs + x1 * sn;
    size_t o = ((size_t)(b * G_ + g) * S_ + s) * DH_;
    kc[o + d]      = r1;
    kc[o + d + 64] = r2;
    kb[o + d]      = f2b(r1);
    kb[o + d + 64] = f2b(r2);
}

// ---------------------------------------------------------------------------
// v: emit v_cache f32 [B][G][S][DH] and v^T bf16 [B][G][DH][S]
// grid=(S/32, DH/32, B*G), block=256
// ---------------------------------------------------------------------------
__global__ __launch_bounds__(256) void v_prep(
    const u16* __restrict__ kvraw, float* __restrict__ vc, u16* __restrict__ vt) {
    __shared__ u16 t[32][33];
    const int s0 = blockIdx.x * 32, d0 = blockIdx.y * 32;
    const int bg = blockIdx.z, b = bg >> 2, g = bg & 3;
    const int j = threadIdx.x & 31, i = threadIdx.x >> 5;
#pragma unroll
    for (int p = 0; p < 4; ++p) {
        int s = s0 + i + 8 * p;
        u16 v = kvraw[(size_t)(b * S_ + s) * 1024 + 512 + g * DH_ + d0 + j];
        t[i + 8 * p][j] = v;
        vc[((size_t)bg * S_ + s) * DH_ + d0 + j] = b2f(v);
    }
    __syncthreads();
#pragma unroll
    for (int p = 0; p < 4; ++p)
        vt[((size_t)bg * DH_ + d0 + i + 8 * p) * S_ + s0 + j] = t[j][i + 8 * p];
}

// ---------------------------------------------------------------------------
// Flash attention v2, causal. 4 waves/block; block = 128 q rows.
// grid=(S/128, H, B), block=256.  K/V tiles staged in LDS, shared by waves.
// Wave w handles q rows [q0b + 32w, q0b + 32w + 31].
// LDS row pads chosen so b128 fragment reads are 2-way conflicts (free):
//   Ks row = 136 elems (272B), Vs/Ps row = 72 elems (144B).
// ---------------------------------------------------------------------------
__global__ __launch_bounds__(256) void flash_attn(
    const u16* __restrict__ q, const u16* __restrict__ kb,
    const u16* __restrict__ vt, u16* __restrict__ ctx) {
    __shared__ __align__(16) u16 Ks[64 * 136];       // [kv 64][d 128] pad->136
    __shared__ __align__(16) u16 Vs[128 * 72];       // [d 128][kv 64] pad->72
    __shared__ __align__(16) u16 Ps[4][32 * 72];     // per-wave P tile

    const int tid  = threadIdx.x;
    const int lane = tid & 63;
    const int wave = tid >> 6;
    const int quad = lane >> 4, l16 = lane & 15;
    const int q0b = blockIdx.x * 128;
    const int q0w = q0b + wave * 32;
    const int h = blockIdx.y, b = blockIdx.z;
    const int g = h >> 2;  // H/G = 4
    const u16* Kp = kb + (size_t)(b * G_ + g) * S_ * DH_;
    const u16* Vt = vt + (size_t)(b * G_ + g) * DH_ * S_;
    const float sc = 0.08838834764831843f * 1.4426950408889634f;  // 1/sqrt(128)*log2(e)

    // Q fragments: A-layout [m=lane&15][k=quad*8+j]
    bf16x8_t qf[2][4];
#pragma unroll
    for (int mt = 0; mt < 2; ++mt)
#pragma unroll
        for (int kt = 0; kt < 4; ++kt)
            qf[mt][kt] = *(const bf16x8_t*)(
                q + ((size_t)(b * S_ + q0w + mt * 16 + l16) * H_ + h) * DH_ + kt * 32 + quad * 8);

    f32x4_t o[2][8] = {};
    float m_i[2][4], l_i[2][4];
#pragma unroll
    for (int mt = 0; mt < 2; ++mt)
#pragma unroll
        for (int r = 0; r < 4; ++r) { m_i[mt][r] = NEG_SENTINEL; l_i[mt][r] = 0.f; }

    const int kv_end = q0b + 128;
    for (int kv0 = 0; kv0 < kv_end; kv0 += 64) {
        // --- cooperative stage: K tile 64x128, Vt tile 128x64 ---
#pragma unroll
        for (int i = 0; i < 4; ++i) {
            int c = tid + 256 * i;  // 1024 chunks of 16B each
            int rk = c >> 4, ck = (c & 15) << 3;
            *(uint4*)(&Ks[rk * 136 + ck]) =
                *(const uint4*)(Kp + (size_t)(kv0 + rk) * DH_ + ck);
            int rv = c >> 3, cv = (c & 7) << 3;
            *(uint4*)(&Vs[rv * 72 + cv]) =
                *(const uint4*)(Vt + (size_t)rv * S_ + kv0 + cv);
        }
        __syncthreads();

        if (kv0 <= q0w + 31) {  // this wave still has unmasked columns
            // S = Q K^T  (2 m-tiles x 4 n-tiles, K=128 over 4 steps)
            f32x4_t s[2][4] = {};
#pragma unroll
            for (int kt = 0; kt < 4; ++kt) {
                bf16x8_t kbf[4];
#pragma unroll
                for (int nt = 0; nt < 4; ++nt)
                    kbf[nt] = *(const bf16x8_t*)(
                        &Ks[(nt * 16 + l16) * 136 + kt * 32 + quad * 8]);
#pragma unroll
                for (int mt = 0; mt < 2; ++mt)
#pragma unroll
                    for (int nt = 0; nt < 4; ++nt)
                        s[mt][nt] = __builtin_amdgcn_mfma_f32_16x16x32_bf16(
                            qf[mt][kt], kbf[nt], s[mt][nt], 0, 0, 0);
            }
            // causal mask — finite sentinel, no inf
            if (kv0 + 63 > q0w) {
#pragma unroll
                for (int mt = 0; mt < 2; ++mt)
#pragma unroll
                    for (int nt = 0; nt < 4; ++nt)
#pragma unroll
                        for (int r = 0; r < 4; ++r) {
                            int row = q0w + mt * 16 + quad * 4 + r;
                            int col = kv0 + nt * 16 + l16;
                            if (col > row) s[mt][nt][r] = NEG_SENTINEL;
                        }
            }
            // online softmax
#pragma unroll
            for (int mt = 0; mt < 2; ++mt)
#pragma unroll
                for (int r = 0; r < 4; ++r) {
                    float mx = fmaxf(fmaxf(s[mt][0][r], s[mt][1][r]),
                                     fmaxf(s[mt][2][r], s[mt][3][r]));
#pragma unroll
                    for (int off = 8; off >= 1; off >>= 1)
                        mx = fmaxf(mx, __shfl_xor(mx, off));
                    float mnew  = fmaxf(m_i[mt][r], mx);
                    float alpha = exp2f(fminf((m_i[mt][r] - mnew) * sc, 0.f));
                    m_i[mt][r]  = mnew;
                    float rs = 0.f;
#pragma unroll
                    for (int nt = 0; nt < 4; ++nt) {
                        float p = exp2f(fminf((s[mt][nt][r] - mnew) * sc, 0.f));
                        if (s[mt][nt][r] <= NEG_SENTINEL * 0.5f) p = 0.f;
                        s[mt][nt][r] = p;
                        rs += p;
                    }
#pragma unroll
                    for (int off = 8; off >= 1; off >>= 1)
                        rs += __shfl_xor(rs, off);
                    l_i[mt][r] = l_i[mt][r] * alpha + rs;
#pragma unroll
                    for (int nt = 0; nt < 8; ++nt) o[mt][nt][r] *= alpha;
                }
            // P: C/D layout -> per-wave LDS -> A-operand layout
#pragma unroll
            for (int mt = 0; mt < 2; ++mt)
#pragma unroll
                for (int nt = 0; nt < 4; ++nt)
#pragma unroll
                    for (int r = 0; r < 4; ++r)
                        Ps[wave][(mt * 16 + quad * 4 + r) * 72 + nt * 16 + l16] =
                            f2b(s[mt][nt][r]);
            // O += P V   (same-wave P readback; compiler inserts lgkmcnt)
#pragma unroll
            for (int ks = 0; ks < 2; ++ks) {
                bf16x8_t pa[2];
#pragma unroll
                for (int mt = 0; mt < 2; ++mt)
                    pa[mt] = *(const bf16x8_t*)(
                        &Ps[wave][(mt * 16 + l16) * 72 + ks * 32 + quad * 8]);
#pragma unroll
                for (int nt = 0; nt < 8; ++nt) {
                    bf16x8_t vb = *(const bf16x8_t*)(
                        &Vs[(nt * 16 + l16) * 72 + ks * 32 + quad * 8]);
#pragma unroll
                    for (int mt = 0; mt < 2; ++mt)
                        o[mt][nt] = __builtin_amdgcn_mfma_f32_16x16x32_bf16(
                            pa[mt], vb, o[mt][nt], 0, 0, 0);
                }
            }
        }
        __syncthreads();
    }
    // epilogue
#pragma unroll
    for (int mt = 0; mt < 2; ++mt)
#pragma unroll
        for (int r = 0; r < 4; ++r) {
            float inv = 1.f / l_i[mt][r];
            int s_idx = q0w + mt * 16 + quad * 4 + r;
#pragma unroll
            for (int nt = 0; nt < 8; ++nt)
                ctx[((size_t)(b * S_ + s_idx) * H_ + h) * DH_ + nt * 16 + l16] =
                    f2b(o[mt][nt][r] * inv);
        }
}

// ---------------------------------------------------------------------------
extern "C" void kernel_launch(void* const* d_in, const int* in_sizes, int n_in,
                              void* d_out, int out_size, void* d_ws, size_t ws_size,
                              hipStream_t stream) {
    const float* x  = (const float*)d_in[0];
    const float* Wq = (const float*)d_in[1];
    const float* Wk = (const float*)d_in[2];
    const float* Wv = (const float*)d_in[3];
    const float* Wo = (const float*)d_in[4];
    // d_in[5] = mask (unused; causal computed analytically)

    float* out    = (float*)d_out;                           // [B][S][H*DH]  8,388,608 f32
    float* kc_out = out + (size_t)B_ * S_ * H_ * DH_;        // [B][G][S][DH] 2,097,152 f32
    float* vc_out = kc_out + (size_t)B_ * G_ * S_ * DH_;     // [B][G][S][DH] 2,097,152 f32

    // Borrow `out` f32 region (= 16M u16) as early scratch; both buffers are
    // dead before the final gemm writes `out` (single stream, serialized).
    u16* outw = (u16*)d_out;
    u16* xb   = outw;             // 8M u16, live phases 1-2 (x cast to bf16)
    u16* qraw = outw + 8388608;   // 8M u16, live phases 2-4

    // Workspace: 16M u16 = 32 MiB, phase-safe overlays
    u16* ws    = (u16*)d_ws;
    u16* WqT   = ws;              // 4M, phases 1-2
    u16* WoT   = ws;              // 4M, phases 3-5 (transposed after q-gemm)
    u16* WkvT  = ws + 4194304;    // 2M, phases 1-2
    u16* kb    = ws + 4194304;    // 2M, phases 3-4
    u16* vt    = ws + 6291456;    // 2M, phases 3-4
    u16* kvraw = ws + 8388608;    // 4M, phases 2-3
    u16* ctx   = ws + 8388608;    // 8M, phases 4-5

    dim3 blk(256);
    // phase 1: casts + W transposes
    cast_x<<<dim3(4096), blk, 0, stream>>>(x, xb);
    transpose_f32_bf16<<<dim3(64, 64), blk, 0, stream>>>(Wq, WqT, 2048, 2048);
    transpose_f32_bf16<<<dim3(16, 64), blk, 0, stream>>>(Wk, WkvT, 2048, 512);
    transpose_f32_bf16<<<dim3(16, 64), blk, 0, stream>>>(Wv, WkvT + (size_t)512 * 2048, 2048, 512);

    // phase 2: projections
    gemm_nt<u16><<<dim3(16, 32), blk, 0, stream>>>(xb, WqT, qraw, 4096, 2048, 2048);
    gemm_nt<u16><<<dim3(8, 32),  blk, 0, stream>>>(xb, WkvT, kvraw, 4096, 1024, 2048);

    // phase 3: RoPE + cache outputs (+ Wo transpose into WqT's slot)
    transpose_f32_bf16<<<dim3(64, 64), blk, 0, stream>>>(Wo, WoT, 2048, 2048);
    rope_q<<<dim3(16384), blk, 0, stream>>>(qraw);
    k_prep<<<dim3(4096),  blk, 0, stream>>>(kvraw, kc_out, kb);
    v_prep<<<dim3(64, 4, 8), blk, 0, stream>>>(kvraw, vc_out, vt);

    // phase 4: attention (4-wave blocks, LDS-staged K/V)
    flash_attn<<<dim3(16, 16, 2), blk, 0, stream>>>(qraw, kb, vt, ctx);

    // phase 5: output projection (f32 out)
    gemm_nt<float><<<dim3(16, 32), blk, 0, stream>>>(ctx, WoT, out, 4096, 2048, 2048);
}

// Round 5
// 577.721 us; speedup vs baseline: 1.4902x; 1.2614x over previous
//
#include <hip/hip_runtime.h>
#include <math.h>

typedef unsigned short u16;
typedef __bf16 bf16x8_t __attribute__((ext_vector_type(8)));
typedef float f32x4_t __attribute__((ext_vector_type(4)));

#define B_  2
#define S_  2048
#define D_  2048
#define H_  16
#define G_  4
#define DH_ 128

#define NEG_SENTINEL (-3.0e38f)
// 1/sqrt(128) * log2(e): folded into q at rope time so softmax uses exp2 directly
#define Q_SCALE (0.08838834764831843f * 1.4426950408889634f)

__device__ __forceinline__ float b2f(u16 u) {
    union { unsigned int i; float f; } v; v.i = ((unsigned int)u) << 16; return v.f;
}
__device__ __forceinline__ u16 f2b(float f) {
    union { float f; unsigned int i; } v; v.f = f;
    unsigned int r = v.i + 0x7fffu + ((v.i >> 16) & 1u);  // RNE
    return (u16)(r >> 16);
}
__device__ __forceinline__ void stc(u16* p, float v)   { *p = f2b(v); }
__device__ __forceinline__ void stc(float* p, float v) { *p = v; }

// ---------------------------------------------------------------------------
// Cast f32 -> bf16, 8 elems/thread.
// ---------------------------------------------------------------------------
__global__ __launch_bounds__(256) void cast_x(
    const float* __restrict__ in, u16* __restrict__ out) {
    int i = (blockIdx.x * 256 + threadIdx.x) * 8;
    float4 a = *(const float4*)(in + i);
    float4 b = *(const float4*)(in + i + 4);
    u16 o[8] = {f2b(a.x), f2b(a.y), f2b(a.z), f2b(a.w),
                f2b(b.x), f2b(b.y), f2b(b.z), f2b(b.w)};
    *(uint4*)(out + i) = *(uint4*)o;
}

// ---------------------------------------------------------------------------
// Transpose + cast: in f32 [R][C] -> out bf16 [C][R]. grid=(C/32, R/32)
// ---------------------------------------------------------------------------
__global__ __launch_bounds__(256) void transpose_f32_bf16(
    const float* __restrict__ in, u16* __restrict__ out, int R, int C) {
    __shared__ u16 t[32][33];
    const int c0 = blockIdx.x * 32, r0 = blockIdx.y * 32;
    const int j = threadIdx.x & 31, i = threadIdx.x >> 5;  // i in 0..7
#pragma unroll
    for (int p = 0; p < 4; ++p)
        t[i + 8 * p][j] = f2b(in[(size_t)(r0 + i + 8 * p) * C + c0 + j]);
    __syncthreads();
#pragma unroll
    for (int p = 0; p < 4; ++p)
        out[(size_t)(c0 + i + 8 * p) * R + r0 + j] = t[j][i + 8 * p];
}

// ---------------------------------------------------------------------------
// NT GEMM: C[M][N] = A[M][K] * BT[N][K]^T (bf16 in, OT out, f32 acc)
// block = 256 (4 waves), tile 128x128, BK=64. grid=(N/128, M/128)
// ---------------------------------------------------------------------------
template <typename OT>
__global__ __launch_bounds__(256) void gemm_nt(
    const u16* __restrict__ A, const u16* __restrict__ BT, OT* __restrict__ C,
    int M, int N, int K) {
    __shared__ __align__(16) u16 As[128 * 72];
    __shared__ __align__(16) u16 Bs[128 * 72];
    const int tid  = threadIdx.x;
    const int lane = tid & 63;
    const int wave = tid >> 6;
    const int wm = wave >> 1, wn = wave & 1;
    const int quad = lane >> 4, l16 = lane & 15;
    const int m0 = blockIdx.y * 128, n0 = blockIdx.x * 128;

    f32x4_t acc[4][4] = {};

    for (int k0 = 0; k0 < K; k0 += 64) {
#pragma unroll
        for (int c = tid; c < 1024; c += 256) {
            int row = c >> 3, cc = (c & 7) << 3;
            *(uint4*)(&As[row * 72 + cc]) =
                *(const uint4*)(A + (size_t)(m0 + row) * K + k0 + cc);
            *(uint4*)(&Bs[row * 72 + cc]) =
                *(const uint4*)(BT + (size_t)(n0 + row) * K + k0 + cc);
        }
        __syncthreads();
#pragma unroll
        for (int ks = 0; ks < 2; ++ks) {
            const int koff = ks * 32 + quad * 8;
            bf16x8_t a[4], b[4];
#pragma unroll
            for (int mt = 0; mt < 4; ++mt)
                a[mt] = *(const bf16x8_t*)(&As[(wm * 64 + mt * 16 + l16) * 72 + koff]);
#pragma unroll
            for (int nt = 0; nt < 4; ++nt)
                b[nt] = *(const bf16x8_t*)(&Bs[(wn * 64 + nt * 16 + l16) * 72 + koff]);
#pragma unroll
            for (int mt = 0; mt < 4; ++mt)
#pragma unroll
                for (int nt = 0; nt < 4; ++nt)
                    acc[mt][nt] = __builtin_amdgcn_mfma_f32_16x16x32_bf16(
                        a[mt], b[nt], acc[mt][nt], 0, 0, 0);
        }
        __syncthreads();
    }
#pragma unroll
    for (int mt = 0; mt < 4; ++mt)
#pragma unroll
        for (int nt = 0; nt < 4; ++nt)
#pragma unroll
            for (int r = 0; r < 4; ++r) {
                int m = m0 + wm * 64 + mt * 16 + quad * 4 + r;
                int n = n0 + wn * 64 + nt * 16 + l16;
                stc(C + (size_t)m * N + n, acc[mt][nt][r]);
            }
}

// ---------------------------------------------------------------------------
// RoPE on q in-place (bf16), folding Q_SCALE (softmax scale * log2e) into q.
// q layout [B][S][H][DH].
// ---------------------------------------------------------------------------
__global__ __launch_bounds__(256) void rope_q(u16* q) {
    int idx = blockIdx.x * 256 + threadIdx.x;
    int d = idx & 63;
    int t = idx >> 6;
    int h = t & 15; t >>= 4;
    int s = t & 2047;
    int b = t >> 11;
    size_t base = ((size_t)(b * S_ + s) * H_ + h) * DH_;
    float x1 = b2f(q[base + d]), x2 = b2f(q[base + d + 64]);
    float inv = exp2f(-(float)d * (13.287712379549449f / 64.f));  // 10000^(-d/64)
    float ang = (float)s * inv, sn, cs;
    sincosf(ang, &sn, &cs);
    q[base + d]      = f2b((x1 * cs - x2 * sn) * Q_SCALE);
    q[base + d + 64] = f2b((x2 * cs + x1 * sn) * Q_SCALE);
}

// ---------------------------------------------------------------------------
// RoPE on k: kvraw bf16 [B*S][1024] (cols 0..511 = k) ->
//   kc f32 [B][G][S][DH] (output) and kb bf16 same layout (for MFMA)
// ---------------------------------------------------------------------------
__global__ __launch_bounds__(256) void k_prep(
    const u16* __restrict__ kvraw, float* __restrict__ kc, u16* __restrict__ kb) {
    int idx = blockIdx.x * 256 + threadIdx.x;
    int d = idx & 63;
    int t = idx >> 6;
    int g = t & 3; t >>= 2;
    int s = t & 2047;
    int b = t >> 11;
    const u16* src = kvraw + (size_t)(b * S_ + s) * 1024 + g * DH_;
    float x1 = b2f(src[d]), x2 = b2f(src[d + 64]);
    float inv = exp2f(-(float)d * (13.287712379549449f / 64.f));
    float ang = (float)s * inv, sn, cs;
    sincosf(ang, &sn, &cs);
    float r1 = x1 * cs - x2 * sn;
    float r2 = x2 * cs + x1 * sn;
    size_t o = ((size_t)(b * G_ + g) * S_ + s) * DH_;
    kc[o + d]      = r1;
    kc[o + d + 64] = r2;
    kb[o + d]      = f2b(r1);
    kb[o + d + 64] = f2b(r2);
}

// ---------------------------------------------------------------------------
// v: emit v_cache f32 [B][G][S][DH] and v^T bf16 [B][G][DH][S]
// grid=(S/32, DH/32, B*G), block=256
// ---------------------------------------------------------------------------
__global__ __launch_bounds__(256) void v_prep(
    const u16* __restrict__ kvraw, float* __restrict__ vc, u16* __restrict__ vt) {
    __shared__ u16 t[32][33];
    const int s0 = blockIdx.x * 32, d0 = blockIdx.y * 32;
    const int bg = blockIdx.z, b = bg >> 2, g = bg & 3;
    const int j = threadIdx.x & 31, i = threadIdx.x >> 5;
#pragma unroll
    for (int p = 0; p < 4; ++p) {
        int s = s0 + i + 8 * p;
        u16 v = kvraw[(size_t)(b * S_ + s) * 1024 + 512 + g * DH_ + d0 + j];
        t[i + 8 * p][j] = v;
        vc[((size_t)bg * S_ + s) * DH_ + d0 + j] = b2f(v);
    }
    __syncthreads();
#pragma unroll
    for (int p = 0; p < 4; ++p)
        vt[((size_t)bg * DH_ + d0 + i + 8 * p) * S_ + s0 + j] = t[j][i + 8 * p];
}

// ---------------------------------------------------------------------------
// Flash attention v3, causal, work-balanced + register-prefetch pipeline.
// grid=(16, H, B), block=256 (4 waves).
// Block x processes q-tiles {x, 31-x} (64 rows each) sequentially: every
// block does exactly 33 kv-iterations (no causal tail skew).
// Wave w handles 16 q rows of the current tile.  K/V tiles staged in LDS
// (rows padded: Ks 136, Vs/Ps 72 -> uniform bank use for b128 frag reads);
// next tile's global loads prefetched into registers during compute.
// q comes pre-scaled by Q_SCALE, so softmax is pure exp2.
// ---------------------------------------------------------------------------
__global__ __launch_bounds__(256, 2) void flash_attn(
    const u16* __restrict__ q, const u16* __restrict__ kb,
    const u16* __restrict__ vt, u16* __restrict__ ctx) {
    __shared__ __align__(16) u16 Ks[64 * 136];       // [kv 64][d 128]
    __shared__ __align__(16) u16 Vs[128 * 72];       // [d 128][kv 64]
    __shared__ __align__(16) u16 Ps[4][16 * 72];     // per-wave P tile

    const int tid  = threadIdx.x;
    const int lane = tid & 63;
    const int wave = tid >> 6;
    const int quad = lane >> 4, l16 = lane & 15;
    const int h = blockIdx.y, b = blockIdx.z;
    const int g = h >> 2;  // H/G = 4
    const u16* Kp = kb + (size_t)(b * G_ + g) * S_ * DH_;
    const u16* Vt = vt + (size_t)(b * G_ + g) * DH_ * S_;

    // staging chunk coords (4 chunks of 16B per thread for each of K,V)
    int krow[4], kcol[4], vrow[4], vcol[4];
#pragma unroll
    for (int i = 0; i < 4; ++i) {
        int c = tid + 256 * i;
        krow[i] = c >> 4; kcol[i] = (c & 15) << 3;
        vrow[i] = c >> 3; vcol[i] = (c & 7) << 3;
    }

#pragma unroll
    for (int half = 0; half < 2; ++half) {
        const int tile = half ? (31 - blockIdx.x) : blockIdx.x;
        const int t0 = tile * 64;
        const int q0w = t0 + wave * 16;
        const int kvend = t0 + 64;

        // Q fragments: A-layout [m=lane&15][k=quad*8+j]
        bf16x8_t qf[4];
#pragma unroll
        for (int kt = 0; kt < 4; ++kt)
            qf[kt] = *(const bf16x8_t*)(
                q + ((size_t)(b * S_ + q0w + l16) * H_ + h) * DH_ + kt * 32 + quad * 8);

        f32x4_t o[8] = {};
        float m_i[4], l_i[4];
#pragma unroll
        for (int r = 0; r < 4; ++r) { m_i[r] = NEG_SENTINEL; l_i[r] = 0.f; }

        // preload kv-tile 0
        uint4 kreg[4], vreg[4];
#pragma unroll
        for (int i = 0; i < 4; ++i) {
            kreg[i] = *(const uint4*)(Kp + (size_t)krow[i] * DH_ + kcol[i]);
            vreg[i] = *(const uint4*)(Vt + (size_t)vrow[i] * S_ + vcol[i]);
        }

        for (int kv0 = 0; kv0 < kvend; kv0 += 64) {
            __syncthreads();  // previous compute done reading Ks/Vs
#pragma unroll
            for (int i = 0; i < 4; ++i) {
                *(uint4*)(&Ks[krow[i] * 136 + kcol[i]]) = kreg[i];
                *(uint4*)(&Vs[vrow[i] * 72 + vcol[i]]) = vreg[i];
            }
            if (kv0 + 64 < kvend) {  // prefetch next kv-tile into regs
                int nx = kv0 + 64;
#pragma unroll
                for (int i = 0; i < 4; ++i) {
                    kreg[i] = *(const uint4*)(Kp + (size_t)(nx + krow[i]) * DH_ + kcol[i]);
                    vreg[i] = *(const uint4*)(Vt + (size_t)vrow[i] * S_ + nx + vcol[i]);
                }
            }
            __syncthreads();  // Ks/Vs visible

            if (kv0 <= q0w + 15) {
                // S = q-scaled Q K^T  (1 m-tile x 4 n-tiles, K=128)
                f32x4_t s[4] = {};
#pragma unroll
                for (int kt = 0; kt < 4; ++kt) {
                    bf16x8_t kbf[4];
#pragma unroll
                    for (int nt = 0; nt < 4; ++nt)
                        kbf[nt] = *(const bf16x8_t*)(
                            &Ks[(nt * 16 + l16) * 136 + kt * 32 + quad * 8]);
#pragma unroll
                    for (int nt = 0; nt < 4; ++nt)
                        s[nt] = __builtin_amdgcn_mfma_f32_16x16x32_bf16(
                            qf[kt], kbf[nt], s[nt], 0, 0, 0);
                }
                // causal mask (diagonal tile only)
                if (kv0 + 63 > q0w) {
#pragma unroll
                    for (int nt = 0; nt < 4; ++nt)
#pragma unroll
                        for (int r = 0; r < 4; ++r) {
                            int row = q0w + quad * 4 + r;
                            int col = kv0 + nt * 16 + l16;
                            if (col > row) s[nt][r] = NEG_SENTINEL;
                        }
                }
                // online softmax (no clamps needed: args always <= 0; masked
                // entries give exp2(-3e38) = +0; no row is ever fully masked)
#pragma unroll
                for (int r = 0; r < 4; ++r) {
                    float mx = fmaxf(fmaxf(s[0][r], s[1][r]),
                                     fmaxf(s[2][r], s[3][r]));
#pragma unroll
                    for (int off = 8; off >= 1; off >>= 1)
                        mx = fmaxf(mx, __shfl_xor(mx, off));
                    float mnew  = fmaxf(m_i[r], mx);
                    float alpha = exp2f(m_i[r] - mnew);
                    m_i[r] = mnew;
                    float rs = 0.f;
#pragma unroll
                    for (int nt = 0; nt < 4; ++nt) {
                        float p = exp2f(s[nt][r] - mnew);
                        s[nt][r] = p;
                        rs += p;
                    }
#pragma unroll
                    for (int off = 8; off >= 1; off >>= 1)
                        rs += __shfl_xor(rs, off);
                    l_i[r] = l_i[r] * alpha + rs;
#pragma unroll
                    for (int nt = 0; nt < 8; ++nt) o[nt][r] *= alpha;
                }
                // P: C/D layout -> per-wave LDS -> A-operand layout
#pragma unroll
                for (int nt = 0; nt < 4; ++nt)
#pragma unroll
                    for (int r = 0; r < 4; ++r)
                        Ps[wave][(quad * 4 + r) * 72 + nt * 16 + l16] = f2b(s[nt][r]);
                // O += P V
#pragma unroll
                for (int ks = 0; ks < 2; ++ks) {
                    bf16x8_t pa = *(const bf16x8_t*)(
                        &Ps[wave][l16 * 72 + ks * 32 + quad * 8]);
#pragma unroll
                    for (int nt = 0; nt < 8; ++nt) {
                        bf16x8_t vb = *(const bf16x8_t*)(
                            &Vs[(nt * 16 + l16) * 72 + ks * 32 + quad * 8]);
                        o[nt] = __builtin_amdgcn_mfma_f32_16x16x32_bf16(
                            pa, vb, o[nt], 0, 0, 0);
                    }
                }
            }
        }
        // epilogue for this tile
#pragma unroll
        for (int r = 0; r < 4; ++r) {
            float inv = 1.f / l_i[r];
            int s_idx = q0w + quad * 4 + r;
#pragma unroll
            for (int nt = 0; nt < 8; ++nt)
                ctx[((size_t)(b * S_ + s_idx) * H_ + h) * DH_ + nt * 16 + l16] =
                    f2b(o[nt][r] * inv);
        }
        __syncthreads();  // all waves done with Ks/Vs before next half restages
    }
}

// ---------------------------------------------------------------------------
extern "C" void kernel_launch(void* const* d_in, const int* in_sizes, int n_in,
                              void* d_out, int out_size, void* d_ws, size_t ws_size,
                              hipStream_t stream) {
    const float* x  = (const float*)d_in[0];
    const float* Wq = (const float*)d_in[1];
    const float* Wk = (const float*)d_in[2];
    const float* Wv = (const float*)d_in[3];
    const float* Wo = (const float*)d_in[4];
    // d_in[5] = mask (unused; causal computed analytically)

    float* out    = (float*)d_out;                           // [B][S][H*DH]  8,388,608 f32
    float* kc_out = out + (size_t)B_ * S_ * H_ * DH_;        // [B][G][S][DH] 2,097,152 f32
    float* vc_out = kc_out + (size_t)B_ * G_ * S_ * DH_;     // [B][G][S][DH] 2,097,152 f32

    // Borrow `out` f32 region (= 16M u16) as early scratch; both buffers are
    // dead before the final gemm writes `out` (single stream, serialized).
    u16* outw = (u16*)d_out;
    u16* xb   = outw;             // 8M u16, live phases 1-2 (x cast to bf16)
    u16* qraw = outw + 8388608;   // 8M u16, live phases 2-4

    // Workspace: 16M u16 = 32 MiB, phase-safe overlays
    u16* ws    = (u16*)d_ws;
    u16* WqT   = ws;              // 4M, phases 1-2
    u16* WoT   = ws;              // 4M, phases 3-5 (transposed after q-gemm)
    u16* WkvT  = ws + 4194304;    // 2M, phases 1-2
    u16* kb    = ws + 4194304;    // 2M, phases 3-4
    u16* vt    = ws + 6291456;    // 2M, phases 3-4
    u16* kvraw = ws + 8388608;    // 4M, phases 2-3
    u16* ctx   = ws + 8388608;    // 8M, phases 4-5

    dim3 blk(256);
    // phase 1: casts + W transposes
    cast_x<<<dim3(4096), blk, 0, stream>>>(x, xb);
    transpose_f32_bf16<<<dim3(64, 64), blk, 0, stream>>>(Wq, WqT, 2048, 2048);
    transpose_f32_bf16<<<dim3(16, 64), blk, 0, stream>>>(Wk, WkvT, 2048, 512);
    transpose_f32_bf16<<<dim3(16, 64), blk, 0, stream>>>(Wv, WkvT + (size_t)512 * 2048, 2048, 512);

    // phase 2: projections
    gemm_nt<u16><<<dim3(16, 32), blk, 0, stream>>>(xb, WqT, qraw, 4096, 2048, 2048);
    gemm_nt<u16><<<dim3(8, 32),  blk, 0, stream>>>(xb, WkvT, kvraw, 4096, 1024, 2048);

    // phase 3: RoPE + cache outputs (+ Wo transpose into WqT's slot)
    transpose_f32_bf16<<<dim3(64, 64), blk, 0, stream>>>(Wo, WoT, 2048, 2048);
    rope_q<<<dim3(16384), blk, 0, stream>>>(qraw);
    k_prep<<<dim3(4096),  blk, 0, stream>>>(kvraw, kc_out, kb);
    v_prep<<<dim3(64, 4, 8), blk, 0, stream>>>(kvraw, vc_out, vt);

    // phase 4: attention (balanced pairing + register prefetch)
    flash_attn<<<dim3(16, 16, 2), blk, 0, stream>>>(qraw, kb, vt, ctx);

    // phase 5: output projection (f32 out)
    gemm_nt<float><<<dim3(16, 32), blk, 0, stream>>>(ctx, WoT, out, 4096, 2048, 2048);
}